// Round 21
// baseline (142.091 us; speedup 1.0000x reference)
//
#include <hip/hip_runtime.h>
#include <hip/hip_bf16.h>

#define CDIM 128
#define EDIM 16
#define NEG_SLOPE 0.2f

typedef __attribute__((ext_vector_type(8))) short bf16x8;
typedef __attribute__((ext_vector_type(4))) float f32x4;
typedef __attribute__((ext_vector_type(2))) float f32x2;
typedef unsigned int uint;
typedef unsigned short ushort;

__device__ __forceinline__ ushort f2bf(float f) {
    uint u = __float_as_uint(f);
    return (ushort)((u + 0x7fffu + ((u >> 16) & 1u)) >> 16);
}
__device__ __forceinline__ uint packbf(float lo, float hi) {
    return ((uint)f2bf(hi) << 16) | (uint)f2bf(lo);
}
__device__ __forceinline__ float bflo(uint w) { return __uint_as_float(w << 16); }
__device__ __forceinline__ float bfhi(uint w) { return __uint_as_float(w & 0xffff0000u); }

__device__ __forceinline__ bool redtest(const void* red, int i, int notInt, int notFloat) {
    if (!notInt)        return ((const int*)red)[i] != 0;
    else if (!notFloat) return ((const float*)red)[i] != 0.f;
    else                return ((const unsigned char*)red)[i] != 0;
}

// ---------------- BcatT + w_e + h->bf16 + zero cnt8/flags (streaming partner kernel) ----------
__global__ __launch_bounds__(256) void bcatwe_kernel(const float* __restrict__ Wr, const float* __restrict__ Wi,
                              const float* __restrict__ Wrr, const float* __restrict__ Wri,
                              ushort* __restrict__ BT,
                              const float* __restrict__ WeR, const float* __restrict__ aeR,
                              const float* __restrict__ WeI, const float* __restrict__ aeI,
                              float* __restrict__ we,
                              int* __restrict__ cnt8, int* __restrict__ flags,
                              const float* __restrict__ h, ushort* __restrict__ hbf,
                              int N8, int n4) {
    int gtid = blockIdx.x * 256 + threadIdx.x;
    for (int i = gtid; i < N8; i += gridDim.x * 256) cnt8[i] = 0;
    if (gtid == 0) { flags[0] = 0; flags[1] = 0; flags[2] = 0; }
    if (gtid < n4) {
        f32x4 v = __builtin_nontemporal_load((const f32x4*)h + gtid);
        uint2 o;
        o.x = packbf(v.x, v.y);
        o.y = packbf(v.z, v.w);
        ((uint2*)hbf)[gtid] = o;
    }
    if (blockIdx.x < 256) {
        int idx = blockIdx.x * 256 + threadIdx.x;
        int c = idx >> 7, k = idx & 127;
        const float* srcm;
        if (c < 128)      srcm = Wr;
        else if (c < 256) srcm = Wi;
        else if (c < 384) srcm = Wrr;
        else              srcm = Wri;
        BT[idx] = f2bf(srcm[k * 128 + (c & 127)]);
    } else if (blockIdx.x == 256) {
        int lane = threadIdx.x;
        if (lane < 16) {
            float s = 0.f;
            for (int c = 0; c < CDIM; ++c) s += WeR[lane * CDIM + c] * aeR[c];
            we[lane] = s;
        } else if (lane < 32) {
            int j = lane - 16;
            float s = 0.f;
            for (int c = 0; c < CDIM; ++c) s += WeI[j * CDIM + c] * aeI[c];
            we[16 + j] = s;
        }
    }
}

// ---------------- fused gemm+prep, 50KB LDS -> 3 blocks/CU ----------------
// blocks [0,GB): MFMA GEMM, A staged once, 8 x 64-col B slabs.
// blocks [GB,GB+PB): prep (flags + XCD-copy histogram + e-scalars), no LDS use.
__global__ __launch_bounds__(256) void gemmprep_kernel(
    const ushort* __restrict__ A, const ushort* __restrict__ BT, ushort* __restrict__ C,
    const float* __restrict__ attsr, const float* __restrict__ attdr,
    const float* __restrict__ attsi, const float* __restrict__ attdi,
    float* __restrict__ asr, float* __restrict__ adr,
    float* __restrict__ asi, float* __restrict__ adi, int M, int GB,
    const uint* __restrict__ red, int nwords, int* __restrict__ flags,
    const int* __restrict__ dst, int* __restrict__ cnt8, int* __restrict__ rank,
    const float* __restrict__ ea, const float* __restrict__ we,
    uint* __restrict__ escal4, int N, int E) {
    __shared__ ushort As[128 * 128];   // 32 KiB
    __shared__ ushort Bs[64 * 128];    // 16 KiB
    __shared__ float dots[4][128];     // 2 KiB
    int bid = blockIdx.x;
    int t = threadIdx.x;

    if (bid >= GB) {
        // ---------------- prep path (no LDS, no barriers) ----------------
        int pb = bid - GB;
        int i = pb * 256 + t;
        int c = pb & 7;   // XCD-copy selector (perf heuristic only)
        if (i < nwords) {
            uint w = red[i];
            bool isInt = (w <= 1u);
            bool isFloat = (w == 0u) || (w == 0x3f800000u);
            if (!isInt) atomicOr(&flags[0], 1);
            if (!isFloat) atomicOr(&flags[1], 1);
        }
        if (i < E) {
            int d = dst[i];
            int rk = atomicAdd(&cnt8[c * N + d], 1);
            __builtin_nontemporal_store(rk | (c << 28), rank + i);
            const f32x4* row = (const f32x4*)(ea + (size_t)i * EDIM);
            const float4* we4 = (const float4*)we;
            float er = 0.f, ei = 0.f;
#pragma unroll
            for (int q = 0; q < 4; ++q) {
                f32x4 v = __builtin_nontemporal_load(row + q);
                float4 wr = we4[q], wi = we4[4 + q];
                er += v.x * wr.x + v.y * wr.y + v.z * wr.z + v.w * wr.w;
                ei += v.x * wi.x + v.y * wi.y + v.z * wi.z + v.w * wi.w;
            }
            __builtin_nontemporal_store(packbf(er, ei), escal4 + i);   // lo=er, hi=ei
        }
        return;
    }

    // ---------------- gemm path ----------------
    int lane = t & 63, wv = t >> 6;
    int rb = bid * 128;

    if (t < 128) { dots[0][t] = 0.f; dots[1][t] = 0.f; dots[2][t] = 0.f; dots[3][t] = 0.f; }

    int rsub = wv * 4 + (lane >> 4);   // 0..15
    int c0 = lane & 15;
#pragma unroll
    for (int p = 0; p < 8; ++p) {
        int row = p * 16 + rsub;
        int chunk = c0 ^ (row & 7);
        int gra = rb + row; if (gra > M - 1) gra = M - 1;
        const ushort* ga = A + (size_t)gra * 128 + chunk * 8;
        __builtin_amdgcn_global_load_lds(
            (const __attribute__((address_space(1))) void*)ga,
            (__attribute__((address_space(3))) void*)((char*)As + p * 4096 + wv * 1024),
            16, 0, 0);
    }

    int wr = wv >> 1, wc = wv & 1;
    int l15 = lane & 15, l4 = lane >> 4;
    const char* Ab = (const char*)As;
    const char* Bb = (const char*)Bs;

    for (int s = 0; s < 8; ++s) {      // 8 x 64-col slabs
        // stage B slab s: 64 cols x 128 k (16KB); waves cover p<4
#pragma unroll
        for (int p = 0; p < 4; ++p) {
            int row = p * 16 + rsub;   // 0..63 (col within slab)
            int chunk = c0 ^ (row & 7);
            const ushort* gb = BT + (size_t)(s * 64 + row) * 128 + chunk * 8;
            __builtin_amdgcn_global_load_lds(
                (const __attribute__((address_space(1))) void*)gb,
                (__attribute__((address_space(3))) void*)((char*)Bs + p * 4096 + wv * 1024),
                16, 0, 0);
        }
        __syncthreads();

        f32x4 acc[4][2];
#pragma unroll
        for (int i = 0; i < 4; ++i)
#pragma unroll
            for (int j = 0; j < 2; ++j) acc[i][j] = (f32x4){0.f, 0.f, 0.f, 0.f};

#pragma unroll
        for (int ks = 0; ks < 4; ++ks) {
            bf16x8 a[4], b[2];
#pragma unroll
            for (int f = 0; f < 4; ++f) {
                int row = wr * 64 + f * 16 + l15;
                int ch = (ks * 4 + l4) ^ (row & 7);
                a[f] = *(const bf16x8*)(Ab + row * 256 + ch * 16);
            }
#pragma unroll
            for (int f = 0; f < 2; ++f) {
                int col = wc * 32 + f * 16 + l15;   // 0..63 within slab
                int ch2 = (ks * 4 + l4) ^ (col & 7);
                b[f] = *(const bf16x8*)(Bb + col * 256 + ch2 * 16);
            }
#pragma unroll
            for (int i = 0; i < 4; ++i)
#pragma unroll
                for (int j = 0; j < 2; ++j)
                    acc[i][j] = __builtin_amdgcn_mfma_f32_16x16x32_bf16(a[i], b[j], acc[i][j], 0, 0, 0);
        }

        // attention dots for slabs 0-3 (x_r: 0,1; x_i: 2,3)
        if (s < 4) {
            int var = s >> 1;
            const float* attS = var ? attsi : attsr;
            const float* attD = var ? attdi : attdr;
            float aS[2], aD[2];
#pragma unroll
            for (int j = 0; j < 2; ++j) {
                int c = (s & 1) * 64 + wc * 32 + j * 16 + l15;
                aS[j] = attS[c]; aD[j] = attD[c];
            }
#pragma unroll
            for (int i = 0; i < 4; ++i)
#pragma unroll
                for (int rr = 0; rr < 4; ++rr) {
                    float ps = 0.f, pd = 0.f;
#pragma unroll
                    for (int j = 0; j < 2; ++j) {
                        float v = acc[i][j][rr];
                        ps += v * aS[j]; pd += v * aD[j];
                    }
#pragma unroll
                    for (int d = 1; d < 16; d <<= 1) {
                        ps += __shfl_xor(ps, d); pd += __shfl_xor(pd, d);
                    }
                    if (l15 == 0) {
                        int row = wr * 64 + i * 16 + l4 * 4 + rr;
                        atomicAdd(&dots[var * 2 + 0][row], ps);
                        atomicAdd(&dots[var * 2 + 1][row], pd);
                    }
                }
        }

        // C store for this slab
#pragma unroll
        for (int i = 0; i < 4; ++i) {
            int rl = wr * 64 + i * 16 + l4 * 4;
#pragma unroll
            for (int j = 0; j < 2; ++j) {
                int col = s * 64 + wc * 32 + j * 16 + l15;
#pragma unroll
                for (int r = 0; r < 4; ++r) {
                    int gr = rb + rl + r;
                    if (gr < M) C[(size_t)gr * 512 + col] = f2bf(acc[i][j][r]);
                }
            }
        }
        __syncthreads();
    }

    if (t < 128) {
        int gr = rb + t;
        if (gr < M) {
            asr[gr] = dots[0][t]; adr[gr] = dots[1][t];
            asi[gr] = dots[2][t]; adi[gr] = dots[3][t];
        }
    }
}

// ---------------- scanA: fold cnt8 + block scan + last-block scans bsum ----------------
__global__ __launch_bounds__(256) void scanA_kernel(int* __restrict__ cnt8,
                                                    int* __restrict__ offA,
                                                    int* __restrict__ bsum,
                                                    int* __restrict__ doneCnt,
                                                    int n, int nb) {
    __shared__ int wsum[4];
    __shared__ int s_last;
    int t = threadIdx.x, lane = t & 63, wid = t >> 6;
    if (t == 0) s_last = 0;
    int i0 = blockIdx.x * 1024 + t * 4;
    int v[4];
#pragma unroll
    for (int j = 0; j < 4; ++j) {
        int d = i0 + j;
        int tot = 0;
        if (d < n) {
#pragma unroll
            for (int x = 0; x < 8; ++x) {
                int cv = cnt8[x * n + d];
                cnt8[x * n + d] = tot;
                tot += cv;
            }
        }
        v[j] = tot;
    }
    int s = v[0] + v[1] + v[2] + v[3];
    int incl = s;
#pragma unroll
    for (int d = 1; d < 64; d <<= 1) { int u = __shfl_up(incl, d); if (lane >= d) incl += u; }
    if (lane == 63) wsum[wid] = incl;
    __syncthreads();
    int wpre = 0;
    for (int w = 0; w < wid; ++w) wpre += wsum[w];
    int run = wpre + incl - s;
#pragma unroll
    for (int j = 0; j < 4; ++j) {
        int i = i0 + j;
        if (i < n) offA[i] = run;
        run += v[j];
    }
    if (t == 255) {
        bsum[blockIdx.x] = wpre + incl;
        __threadfence();
        int old = atomicAdd(doneCnt, 1);
        if (old == (int)gridDim.x - 1) s_last = 1;
    }
    __syncthreads();
    if (s_last && t < 64) {
        __threadfence();
        int v2 = (t < nb) ? bsum[t] : 0;
        int incl2 = v2;
#pragma unroll
        for (int d = 1; d < 64; d <<= 1) { int u = __shfl_up(incl2, d); if (t >= d) incl2 += u; }
        if (t < nb) bsum[t] = incl2 - v2;
    }
}

// ---------------- scatter: atomic-free 4B-record CSR permutation ----------------
__global__ __launch_bounds__(256) void scatter_kernel(
    const int* __restrict__ src, const int* __restrict__ dst,
    const int* __restrict__ rank, const uint* __restrict__ escal4,
    const void* __restrict__ red, const int* __restrict__ flags,
    const int* __restrict__ offA, const int* __restrict__ bsum,
    const int* __restrict__ cnt8,
    uint* __restrict__ csr, int N, int E) {
    int e = blockIdx.x * 256 + threadIdx.x;
    if (e >= E) return;
    int s = __builtin_nontemporal_load(src + e);
    int d = __builtin_nontemporal_load(dst + e);
    uint ee = __builtin_nontemporal_load(escal4 + e);
    int rkw = __builtin_nontemporal_load(rank + e);
    int c = ((uint)rkw) >> 28;
    int rk = rkw & 0x0fffffff;
    int notInt = flags[0], notFloat = flags[1];
    bool rr = redtest(red, d, notInt, notFloat);
    uint evb = rr ? (ee & 0xffffu) : (ee >> 16);
    int off = offA[d] + bsum[d >> 10] + cnt8[c * N + d];
    csr[off + rk] = (uint)s | (evb << 16);
}

// ---------------- node kernel: plain softmax + 8-deep gather + residual + select + relu ----
__global__ __launch_bounds__(256) void node_kernel(
    const ushort* __restrict__ xcat,
    const float* __restrict__ adst_r, const float* __restrict__ adst_i,
    const float* __restrict__ asrc_r, const float* __restrict__ asrc_i,
    const void* __restrict__ red, const int* __restrict__ flags,
    const int* __restrict__ offA, const int* __restrict__ bsum,
    const uint* __restrict__ csr,
    const float* __restrict__ bias_r, const float* __restrict__ bias_i,
    float* __restrict__ out, int n, int E) {
    __shared__ uint2 buf[4][64];
    int wv = threadIdx.x >> 6, lane = threadIdx.x & 63;
    int node = blockIdx.x * 4 + wv;
    if (node >= n) return;

    int notInt = flags[0], notFloat = flags[1];
    bool r = redtest(red, node, notInt, notFloat);

    const float* asrc = r ? asrc_r : asrc_i;
    float adst = (r ? adst_r : adst_i)[node];
    uint vsel = r ? 0u : 256u;
    int b0 = offA[node] + bsum[node >> 10];
    int b1 = (node + 1 < n) ? (offA[node + 1] + bsum[(node + 1) >> 10]) : E;
    int k = b1 - b0;
    const char* xb = (const char*)xcat;
    uint lane4 = lane * 4;

    float denom_l = 0.f, sumE = 0.f;
    float2 acca = make_float2(0.f, 0.f), accb = make_float2(0.f, 0.f);

    for (int base = b0; base < b1; base += 64) {
        int j = base + lane;
        float ex = 0.f; uint soff = 0;
        if (j < b1) {
            uint rec = __builtin_nontemporal_load(csr + j);
            uint s = rec & 0xffffu;
            float ev = bfhi(rec);
            sumE += ev;
            soff = s * 1024u + vsel;
            float a = asrc[s] + ev + adst;
            float al = (a >= 0.f) ? a : NEG_SLOPE * a;
            ex = __expf(fminf(al, 60.f));
            denom_l += ex;
        }
        buf[wv][lane] = make_uint2(__float_as_uint(ex), soff);
        __builtin_amdgcn_wave_barrier();
        int cc = min(64, b1 - base);
        int ccp = (cc + 7) & ~7;
        for (int tq = 0; tq < ccp; tq += 8) {
            uint2 u[8];
#pragma unroll
            for (int q = 0; q < 8; ++q) u[q] = buf[wv][tq + q];
            uint v[8];
#pragma unroll
            for (int q = 0; q < 8; ++q) v[q] = *(const uint*)(xb + u[q].y + lane4);
#pragma unroll
            for (int q = 0; q < 4; ++q) {
                float w = __uint_as_float(u[q].x);
                acca.x += w * bflo(v[q]); acca.y += w * bfhi(v[q]);
            }
#pragma unroll
            for (int q = 4; q < 8; ++q) {
                float w = __uint_as_float(u[q].x);
                accb.x += w * bflo(v[q]); accb.y += w * bfhi(v[q]);
            }
        }
        __builtin_amdgcn_wave_barrier();
    }
    float acc0 = acca.x + accb.x, acc1 = acca.y + accb.y;

#pragma unroll
    for (int d = 32; d; d >>= 1) {
        sumE += __shfl_xor(sumE, d);
        denom_l += __shfl_xor(denom_l, d);
    }

    float eself = sumE / fmaxf((float)k, 1.f);
    float a = asrc[node] + adst + eself;
    float aself = (a >= 0.f) ? a : NEG_SLOPE * a;
    float exl = __expf(fminf(aself, 60.f));
    float denom = denom_l + exl;
    uint voff = (uint)node * 1024u + vsel;
    uint vsw = *(const uint*)(xb + voff + lane4);
    acc0 += exl * bflo(vsw);
    acc1 += exl * bfhi(vsw);

    float inv = 1.f / denom;
    uint roff = (uint)node * 1024u + (r ? 512u : 768u);
    uint bw = *(const uint*)(xb + roff + lane4);
    float2 bi2 = ((const float2*)(r ? bias_r : bias_i))[lane];
    f32x2 o;
    o.x = fmaxf(acc0 * inv + bflo(bw) + bi2.x, 0.f);
    o.y = fmaxf(acc1 * inv + bfhi(bw) + bi2.y, 0.f);
    __builtin_nontemporal_store(o, ((f32x2*)out) + (size_t)node * 64 + lane);
}

extern "C" void kernel_launch(void* const* d_in, const int* in_sizes, int n_in,
                              void* d_out, int out_size, void* d_ws, size_t ws_size,
                              hipStream_t stream) {
    const float* h          = (const float*)d_in[0];
    const int*   edge_index = (const int*)d_in[1];
    const float* edge_attr  = (const float*)d_in[2];
    const void*  reducible  = d_in[3];
    const float* red_W      = (const float*)d_in[4];
    const float* red_att_src= (const float*)d_in[5];
    const float* red_att_dst= (const float*)d_in[6];
    const float* red_W_edge = (const float*)d_in[7];
    const float* red_att_edge=(const float*)d_in[8];
    const float* red_W_res  = (const float*)d_in[9];
    const float* red_bias   = (const float*)d_in[10];
    const float* irr_W      = (const float*)d_in[11];
    const float* irr_att_src= (const float*)d_in[12];
    const float* irr_att_dst= (const float*)d_in[13];
    const float* irr_W_edge = (const float*)d_in[14];
    const float* irr_att_edge=(const float*)d_in[15];
    const float* irr_W_res  = (const float*)d_in[16];
    const float* irr_bias   = (const float*)d_in[17];

    const int N = in_sizes[0] / CDIM;
    const int E = in_sizes[1] / 2;
    const int* src = edge_index;
    const int* dst = edge_index + E;
    const int nb = (N + 1023) / 1024;
    const int n4 = N * 128 / 4;

    float* out = (float*)d_out;

    size_t cur = 0;
    auto alloc = [&](size_t bytes) { size_t p = cur; cur = (cur + bytes + 255) & ~(size_t)255; return p; };
    char* ws = (char*)d_ws;
    size_t o_xcat  = alloc((size_t)N * 512 * 2);
    size_t o_hbf   = alloc((size_t)N * 128 * 2);
    size_t o_bcat  = alloc(512 * 128 * 2);
    size_t o_we    = alloc(256);
    size_t o_asr   = alloc((size_t)N * 4);
    size_t o_adr   = alloc((size_t)N * 4);
    size_t o_asi   = alloc((size_t)N * 4);
    size_t o_adi   = alloc((size_t)N * 4);
    size_t o_flags = alloc(256);
    size_t o_cnt8  = alloc((size_t)N * 8 * 4);
    size_t o_offA  = alloc((size_t)N * 4);
    size_t o_bsum  = alloc((size_t)(nb + 1) * 4);
    size_t o_rank  = alloc((size_t)E * 4);
    size_t o_escal = alloc((size_t)E * 4);
    size_t o_csr   = alloc((size_t)E * 4);
    if (cur > ws_size) return;

    ushort* xcat = (ushort*)(ws + o_xcat);
    ushort* hbf  = (ushort*)(ws + o_hbf);
    ushort* bcat = (ushort*)(ws + o_bcat);
    float* we    = (float*)(ws + o_we);
    float* asr   = (float*)(ws + o_asr);
    float* adr   = (float*)(ws + o_adr);
    float* asi   = (float*)(ws + o_asi);
    float* adi   = (float*)(ws + o_adi);
    int*   flags = (int*)(ws + o_flags);
    int*   cnt8  = (int*)(ws + o_cnt8);
    int*   offA  = (int*)(ws + o_offA);
    int*   bsum  = (int*)(ws + o_bsum);
    int*   rank  = (int*)(ws + o_rank);
    uint*  escal4= (uint*)(ws + o_escal);
    uint*  csr   = (uint*)(ws + o_csr);

    int N8 = N * 8;
    int bgrid = (n4 + 255) / 256;
    if (bgrid < 257) bgrid = 257;
    bcatwe_kernel<<<bgrid, 256, 0, stream>>>(red_W, irr_W, red_W_res, irr_W_res, bcat,
                                             red_W_edge, red_att_edge, irr_W_edge, irr_att_edge, we,
                                             cnt8, flags, h, hbf, N8, n4);

    int nwords = N / 4;
    int GB = (N + 127) / 128;
    int PB = (E + 255) / 256;
    gemmprep_kernel<<<GB + PB, 256, 0, stream>>>(hbf, bcat, xcat,
                                                 red_att_src, red_att_dst,
                                                 irr_att_src, irr_att_dst,
                                                 asr, adr, asi, adi, N, GB,
                                                 (const uint*)reducible, nwords, flags,
                                                 dst, cnt8, rank, edge_attr, we, escal4, N, E);

    scanA_kernel<<<nb, 256, 0, stream>>>(cnt8, offA, bsum, flags + 2, N, nb);

    scatter_kernel<<<(E + 255) / 256, 256, 0, stream>>>(src, dst, rank, escal4,
                                                        reducible, flags, offA, bsum, cnt8,
                                                        csr, N, E);

    node_kernel<<<(N + 3) / 4, 256, 0, stream>>>(xcat, adr, adi, asr, asi,
                                                 reducible, flags, offA, bsum, csr,
                                                 red_bias, irr_bias, out, N, E);
}

// Round 22
// 140.854 us; speedup vs baseline: 1.0088x; 1.0088x over previous
//
#include <hip/hip_runtime.h>
#include <hip/hip_bf16.h>

#define CDIM 128
#define EDIM 16
#define NEG_SLOPE 0.2f

typedef __attribute__((ext_vector_type(8))) short bf16x8;
typedef __attribute__((ext_vector_type(4))) float f32x4;
typedef __attribute__((ext_vector_type(2))) float f32x2;
typedef unsigned int uint;
typedef unsigned short ushort;

__device__ __forceinline__ ushort f2bf(float f) {
    uint u = __float_as_uint(f);
    return (ushort)((u + 0x7fffu + ((u >> 16) & 1u)) >> 16);
}
__device__ __forceinline__ uint packbf(float lo, float hi) {
    return ((uint)f2bf(hi) << 16) | (uint)f2bf(lo);
}
__device__ __forceinline__ float bflo(uint w) { return __uint_as_float(w << 16); }
__device__ __forceinline__ float bfhi(uint w) { return __uint_as_float(w & 0xffff0000u); }

__device__ __forceinline__ bool redtest(const void* red, int i, int notInt, int notFloat) {
    if (!notInt)        return ((const int*)red)[i] != 0;
    else if (!notFloat) return ((const float*)red)[i] != 0.f;
    else                return ((const unsigned char*)red)[i] != 0;
}

// ---------------- BcatT + w_e + zero cnt8/flags (small setup kernel, ~3us) ----------------
__global__ __launch_bounds__(256) void bcatwe_kernel(const float* __restrict__ Wr, const float* __restrict__ Wi,
                              const float* __restrict__ Wrr, const float* __restrict__ Wri,
                              ushort* __restrict__ BT,
                              const float* __restrict__ WeR, const float* __restrict__ aeR,
                              const float* __restrict__ WeI, const float* __restrict__ aeI,
                              float* __restrict__ we,
                              int* __restrict__ cnt8, int* __restrict__ flags, int N8) {
    int gtid = blockIdx.x * 256 + threadIdx.x;
    for (int i = gtid; i < N8; i += gridDim.x * 256) cnt8[i] = 0;
    if (gtid == 0) { flags[0] = 0; flags[1] = 0; flags[2] = 0; }
    if (blockIdx.x < 256) {
        int idx = blockIdx.x * 256 + threadIdx.x;
        int c = idx >> 7, k = idx & 127;
        const float* srcm;
        if (c < 128)      srcm = Wr;
        else if (c < 256) srcm = Wi;
        else if (c < 384) srcm = Wrr;
        else              srcm = Wri;
        BT[idx] = f2bf(srcm[k * 128 + (c & 127)]);
    } else if (blockIdx.x == 256) {
        int lane = threadIdx.x;
        if (lane < 16) {
            float s = 0.f;
            for (int c = 0; c < CDIM; ++c) s += WeR[lane * CDIM + c] * aeR[c];
            we[lane] = s;
        } else if (lane < 32) {
            int j = lane - 16;
            float s = 0.f;
            for (int c = 0; c < CDIM; ++c) s += WeI[j * CDIM + c] * aeI[c];
            we[16 + j] = s;
        }
    }
}

// ---------------- fused gemm+prep, 50KB LDS -> 3 blocks/CU ----------------
// blocks [0,GB): MFMA GEMM; A reg-staged from f32 h (read-once) with bf16 pack + swizzled
// ds_write; 8 x 64-col B slabs. blocks [GB,GB+PB): prep (flags + histogram + e-scalars).
__global__ __launch_bounds__(256) void gemmprep_kernel(
    const float* __restrict__ h, const ushort* __restrict__ BT, ushort* __restrict__ C,
    const float* __restrict__ attsr, const float* __restrict__ attdr,
    const float* __restrict__ attsi, const float* __restrict__ attdi,
    float* __restrict__ asr, float* __restrict__ adr,
    float* __restrict__ asi, float* __restrict__ adi, int M, int GB,
    const uint* __restrict__ red, int nwords, int* __restrict__ flags,
    const int* __restrict__ dst, int* __restrict__ cnt8, int* __restrict__ rank,
    const float* __restrict__ ea, const float* __restrict__ we,
    uint* __restrict__ escal4, int N, int E) {
    __shared__ ushort As[128 * 128];   // 32 KiB
    __shared__ ushort Bs[64 * 128];    // 16 KiB
    __shared__ float dots[4][128];     // 2 KiB
    int bid = blockIdx.x;
    int t = threadIdx.x;

    if (bid >= GB) {
        // ---------------- prep path (no LDS, no barriers) ----------------
        int pb = bid - GB;
        int i = pb * 256 + t;
        int c = pb & 7;   // XCD-copy selector (perf heuristic only)
        if (i < nwords) {
            uint w = red[i];
            bool isInt = (w <= 1u);
            bool isFloat = (w == 0u) || (w == 0x3f800000u);
            if (!isInt) atomicOr(&flags[0], 1);
            if (!isFloat) atomicOr(&flags[1], 1);
        }
        if (i < E) {
            int d = dst[i];
            int rk = atomicAdd(&cnt8[c * N + d], 1);
            __builtin_nontemporal_store(rk | (c << 28), rank + i);
            const f32x4* row = (const f32x4*)(ea + (size_t)i * EDIM);
            const float4* we4 = (const float4*)we;
            float er = 0.f, ei = 0.f;
#pragma unroll
            for (int q = 0; q < 4; ++q) {
                f32x4 v = __builtin_nontemporal_load(row + q);
                float4 wr = we4[q], wi = we4[4 + q];
                er += v.x * wr.x + v.y * wr.y + v.z * wr.z + v.w * wr.w;
                ei += v.x * wi.x + v.y * wi.y + v.z * wi.z + v.w * wi.w;
            }
            __builtin_nontemporal_store(packbf(er, ei), escal4 + i);   // lo=er, hi=ei
        }
        return;
    }

    // ---------------- gemm path ----------------
    int lane = t & 63, wv = t >> 6;
    int rb = bid * 128;

    if (t < 128) { dots[0][t] = 0.f; dots[1][t] = 0.f; dots[2][t] = 0.f; dots[3][t] = 0.f; }

    // stage A[128][128]: f32 -> bf16 pack -> swizzled ds_write_b128 (h read once per row)
    {
        int row = t >> 1, half = t & 1;
        int gra = rb + row; if (gra > M - 1) gra = M - 1;
        const float4* hp = (const float4*)(h + (size_t)gra * 128 + half * 64);
#pragma unroll
        for (int k = 0; k < 8; ++k) {
            float4 a = hp[2 * k], b = hp[2 * k + 1];
            uint4 o;
            o.x = packbf(a.x, a.y); o.y = packbf(a.z, a.w);
            o.z = packbf(b.x, b.y); o.w = packbf(b.z, b.w);
            int cc = half * 8 + k;
            *(uint4*)((char*)As + row * 256 + (cc ^ (row & 7)) * 16) = o;
        }
    }

    int rsub = wv * 4 + (lane >> 4);   // 0..15
    int c0 = lane & 15;
    int wr = wv >> 1, wc = wv & 1;
    int l15 = lane & 15, l4 = lane >> 4;
    const char* Ab = (const char*)As;
    const char* Bb = (const char*)Bs;

    for (int s = 0; s < 8; ++s) {      // 8 x 64-col slabs
#pragma unroll
        for (int p = 0; p < 4; ++p) {
            int row = p * 16 + rsub;   // 0..63 (col within slab)
            int chunk = c0 ^ (row & 7);
            const ushort* gb = BT + (size_t)(s * 64 + row) * 128 + chunk * 8;
            __builtin_amdgcn_global_load_lds(
                (const __attribute__((address_space(1))) void*)gb,
                (__attribute__((address_space(3))) void*)((char*)Bs + p * 4096 + wv * 1024),
                16, 0, 0);
        }
        __syncthreads();

        f32x4 acc[4][2];
#pragma unroll
        for (int i = 0; i < 4; ++i)
#pragma unroll
            for (int j = 0; j < 2; ++j) acc[i][j] = (f32x4){0.f, 0.f, 0.f, 0.f};

#pragma unroll
        for (int ks = 0; ks < 4; ++ks) {
            bf16x8 a[4], b[2];
#pragma unroll
            for (int f = 0; f < 4; ++f) {
                int row = wr * 64 + f * 16 + l15;
                int ch = (ks * 4 + l4) ^ (row & 7);
                a[f] = *(const bf16x8*)(Ab + row * 256 + ch * 16);
            }
#pragma unroll
            for (int f = 0; f < 2; ++f) {
                int col = wc * 32 + f * 16 + l15;   // 0..63 within slab
                int ch2 = (ks * 4 + l4) ^ (col & 7);
                b[f] = *(const bf16x8*)(Bb + col * 256 + ch2 * 16);
            }
#pragma unroll
            for (int i = 0; i < 4; ++i)
#pragma unroll
                for (int j = 0; j < 2; ++j)
                    acc[i][j] = __builtin_amdgcn_mfma_f32_16x16x32_bf16(a[i], b[j], acc[i][j], 0, 0, 0);
        }

        if (s < 4) {
            int var = s >> 1;
            const float* attS = var ? attsi : attsr;
            const float* attD = var ? attdi : attdr;
            float aS[2], aD[2];
#pragma unroll
            for (int j = 0; j < 2; ++j) {
                int c = (s & 1) * 64 + wc * 32 + j * 16 + l15;
                aS[j] = attS[c]; aD[j] = attD[c];
            }
#pragma unroll
            for (int i = 0; i < 4; ++i)
#pragma unroll
                for (int rr = 0; rr < 4; ++rr) {
                    float ps = 0.f, pd = 0.f;
#pragma unroll
                    for (int j = 0; j < 2; ++j) {
                        float v = acc[i][j][rr];
                        ps += v * aS[j]; pd += v * aD[j];
                    }
#pragma unroll
                    for (int d = 1; d < 16; d <<= 1) {
                        ps += __shfl_xor(ps, d); pd += __shfl_xor(pd, d);
                    }
                    if (l15 == 0) {
                        int row = wr * 64 + i * 16 + l4 * 4 + rr;
                        atomicAdd(&dots[var * 2 + 0][row], ps);
                        atomicAdd(&dots[var * 2 + 1][row], pd);
                    }
                }
        }

#pragma unroll
        for (int i = 0; i < 4; ++i) {
            int rl = wr * 64 + i * 16 + l4 * 4;
#pragma unroll
            for (int j = 0; j < 2; ++j) {
                int col = s * 64 + wc * 32 + j * 16 + l15;
#pragma unroll
                for (int r = 0; r < 4; ++r) {
                    int gr = rb + rl + r;
                    if (gr < M) C[(size_t)gr * 512 + col] = f2bf(acc[i][j][r]);
                }
            }
        }
        __syncthreads();
    }

    if (t < 128) {
        int gr = rb + t;
        if (gr < M) {
            asr[gr] = dots[0][t]; adr[gr] = dots[1][t];
            asi[gr] = dots[2][t]; adi[gr] = dots[3][t];
        }
    }
}

// ---------------- scanA: fold cnt8 + block scan + last-block scans bsum ----------------
__global__ __launch_bounds__(256) void scanA_kernel(int* __restrict__ cnt8,
                                                    int* __restrict__ offA,
                                                    int* __restrict__ bsum,
                                                    int* __restrict__ doneCnt,
                                                    int n, int nb) {
    __shared__ int wsum[4];
    __shared__ int s_last;
    int t = threadIdx.x, lane = t & 63, wid = t >> 6;
    if (t == 0) s_last = 0;
    int i0 = blockIdx.x * 1024 + t * 4;
    int v[4];
#pragma unroll
    for (int j = 0; j < 4; ++j) {
        int d = i0 + j;
        int tot = 0;
        if (d < n) {
#pragma unroll
            for (int x = 0; x < 8; ++x) {
                int cv = cnt8[x * n + d];
                cnt8[x * n + d] = tot;
                tot += cv;
            }
        }
        v[j] = tot;
    }
    int s = v[0] + v[1] + v[2] + v[3];
    int incl = s;
#pragma unroll
    for (int d = 1; d < 64; d <<= 1) { int u = __shfl_up(incl, d); if (lane >= d) incl += u; }
    if (lane == 63) wsum[wid] = incl;
    __syncthreads();
    int wpre = 0;
    for (int w = 0; w < wid; ++w) wpre += wsum[w];
    int run = wpre + incl - s;
#pragma unroll
    for (int j = 0; j < 4; ++j) {
        int i = i0 + j;
        if (i < n) offA[i] = run;
        run += v[j];
    }
    if (t == 255) {
        bsum[blockIdx.x] = wpre + incl;
        __threadfence();
        int old = atomicAdd(doneCnt, 1);
        if (old == (int)gridDim.x - 1) s_last = 1;
    }
    __syncthreads();
    if (s_last && t < 64) {
        __threadfence();
        int v2 = (t < nb) ? bsum[t] : 0;
        int incl2 = v2;
#pragma unroll
        for (int d = 1; d < 64; d <<= 1) { int u = __shfl_up(incl2, d); if (t >= d) incl2 += u; }
        if (t < nb) bsum[t] = incl2 - v2;
    }
}

// ---------------- scatter: atomic-free 4B-record CSR permutation ----------------
__global__ __launch_bounds__(256) void scatter_kernel(
    const int* __restrict__ src, const int* __restrict__ dst,
    const int* __restrict__ rank, const uint* __restrict__ escal4,
    const void* __restrict__ red, const int* __restrict__ flags,
    const int* __restrict__ offA, const int* __restrict__ bsum,
    const int* __restrict__ cnt8,
    uint* __restrict__ csr, int N, int E) {
    int e = blockIdx.x * 256 + threadIdx.x;
    if (e >= E) return;
    int s = __builtin_nontemporal_load(src + e);
    int d = __builtin_nontemporal_load(dst + e);
    uint ee = __builtin_nontemporal_load(escal4 + e);
    int rkw = __builtin_nontemporal_load(rank + e);
    int c = ((uint)rkw) >> 28;
    int rk = rkw & 0x0fffffff;
    int notInt = flags[0], notFloat = flags[1];
    bool rr = redtest(red, d, notInt, notFloat);
    uint evb = rr ? (ee & 0xffffu) : (ee >> 16);
    int off = offA[d] + bsum[d >> 10] + cnt8[c * N + d];
    csr[off + rk] = (uint)s | (evb << 16);
}

// ---------------- node kernel: plain softmax + 8-deep gather + residual + select + relu ----
__global__ __launch_bounds__(256) void node_kernel(
    const ushort* __restrict__ xcat,
    const float* __restrict__ adst_r, const float* __restrict__ adst_i,
    const float* __restrict__ asrc_r, const float* __restrict__ asrc_i,
    const void* __restrict__ red, const int* __restrict__ flags,
    const int* __restrict__ offA, const int* __restrict__ bsum,
    const uint* __restrict__ csr,
    const float* __restrict__ bias_r, const float* __restrict__ bias_i,
    float* __restrict__ out, int n, int E) {
    __shared__ uint2 buf[4][64];
    int wv = threadIdx.x >> 6, lane = threadIdx.x & 63;
    int node = blockIdx.x * 4 + wv;
    if (node >= n) return;

    int notInt = flags[0], notFloat = flags[1];
    bool r = redtest(red, node, notInt, notFloat);

    const float* asrc = r ? asrc_r : asrc_i;
    float adst = (r ? adst_r : adst_i)[node];
    uint vsel = r ? 0u : 256u;
    int b0 = offA[node] + bsum[node >> 10];
    int b1 = (node + 1 < n) ? (offA[node + 1] + bsum[(node + 1) >> 10]) : E;
    int k = b1 - b0;
    const char* xb = (const char*)xcat;
    uint lane4 = lane * 4;

    float denom_l = 0.f, sumE = 0.f;
    float2 acca = make_float2(0.f, 0.f), accb = make_float2(0.f, 0.f);

    for (int base = b0; base < b1; base += 64) {
        int j = base + lane;
        float ex = 0.f; uint soff = 0;
        if (j < b1) {
            uint rec = __builtin_nontemporal_load(csr + j);
            uint s = rec & 0xffffu;
            float ev = bfhi(rec);
            sumE += ev;
            soff = s * 1024u + vsel;
            float a = asrc[s] + ev + adst;
            float al = (a >= 0.f) ? a : NEG_SLOPE * a;
            ex = __expf(fminf(al, 60.f));
            denom_l += ex;
        }
        buf[wv][lane] = make_uint2(__float_as_uint(ex), soff);
        __builtin_amdgcn_wave_barrier();
        int cc = min(64, b1 - base);
        int ccp = (cc + 7) & ~7;
        for (int tq = 0; tq < ccp; tq += 8) {
            uint2 u[8];
#pragma unroll
            for (int q = 0; q < 8; ++q) u[q] = buf[wv][tq + q];
            uint v[8];
#pragma unroll
            for (int q = 0; q < 8; ++q) v[q] = *(const uint*)(xb + u[q].y + lane4);
#pragma unroll
            for (int q = 0; q < 4; ++q) {
                float w = __uint_as_float(u[q].x);
                acca.x += w * bflo(v[q]); acca.y += w * bfhi(v[q]);
            }
#pragma unroll
            for (int q = 4; q < 8; ++q) {
                float w = __uint_as_float(u[q].x);
                accb.x += w * bflo(v[q]); accb.y += w * bfhi(v[q]);
            }
        }
        __builtin_amdgcn_wave_barrier();
    }
    float acc0 = acca.x + accb.x, acc1 = acca.y + accb.y;

#pragma unroll
    for (int d = 32; d; d >>= 1) {
        sumE += __shfl_xor(sumE, d);
        denom_l += __shfl_xor(denom_l, d);
    }

    float eself = sumE / fmaxf((float)k, 1.f);
    float a = asrc[node] + adst + eself;
    float aself = (a >= 0.f) ? a : NEG_SLOPE * a;
    float exl = __expf(fminf(aself, 60.f));
    float denom = denom_l + exl;
    uint voff = (uint)node * 1024u + vsel;
    uint vsw = *(const uint*)(xb + voff + lane4);
    acc0 += exl * bflo(vsw);
    acc1 += exl * bfhi(vsw);

    float inv = 1.f / denom;
    uint roff = (uint)node * 1024u + (r ? 512u : 768u);
    uint bw = *(const uint*)(xb + roff + lane4);
    float2 bi2 = ((const float2*)(r ? bias_r : bias_i))[lane];
    f32x2 o;
    o.x = fmaxf(acc0 * inv + bflo(bw) + bi2.x, 0.f);
    o.y = fmaxf(acc1 * inv + bfhi(bw) + bi2.y, 0.f);
    __builtin_nontemporal_store(o, ((f32x2*)out) + (size_t)node * 64 + lane);
}

extern "C" void kernel_launch(void* const* d_in, const int* in_sizes, int n_in,
                              void* d_out, int out_size, void* d_ws, size_t ws_size,
                              hipStream_t stream) {
    const float* h          = (const float*)d_in[0];
    const int*   edge_index = (const int*)d_in[1];
    const float* edge_attr  = (const float*)d_in[2];
    const void*  reducible  = d_in[3];
    const float* red_W      = (const float*)d_in[4];
    const float* red_att_src= (const float*)d_in[5];
    const float* red_att_dst= (const float*)d_in[6];
    const float* red_W_edge = (const float*)d_in[7];
    const float* red_att_edge=(const float*)d_in[8];
    const float* red_W_res  = (const float*)d_in[9];
    const float* red_bias   = (const float*)d_in[10];
    const float* irr_W      = (const float*)d_in[11];
    const float* irr_att_src= (const float*)d_in[12];
    const float* irr_att_dst= (const float*)d_in[13];
    const float* irr_W_edge = (const float*)d_in[14];
    const float* irr_att_edge=(const float*)d_in[15];
    const float* irr_W_res  = (const float*)d_in[16];
    const float* irr_bias   = (const float*)d_in[17];

    const int N = in_sizes[0] / CDIM;
    const int E = in_sizes[1] / 2;
    const int* src = edge_index;
    const int* dst = edge_index + E;
    const int nb = (N + 1023) / 1024;

    float* out = (float*)d_out;

    size_t cur = 0;
    auto alloc = [&](size_t bytes) { size_t p = cur; cur = (cur + bytes + 255) & ~(size_t)255; return p; };
    char* ws = (char*)d_ws;
    size_t o_xcat  = alloc((size_t)N * 512 * 2);
    size_t o_bcat  = alloc(512 * 128 * 2);
    size_t o_we    = alloc(256);
    size_t o_asr   = alloc((size_t)N * 4);
    size_t o_adr   = alloc((size_t)N * 4);
    size_t o_asi   = alloc((size_t)N * 4);
    size_t o_adi   = alloc((size_t)N * 4);
    size_t o_flags = alloc(256);
    size_t o_cnt8  = alloc((size_t)N * 8 * 4);
    size_t o_offA  = alloc((size_t)N * 4);
    size_t o_bsum  = alloc((size_t)(nb + 1) * 4);
    size_t o_rank  = alloc((size_t)E * 4);
    size_t o_escal = alloc((size_t)E * 4);
    size_t o_csr   = alloc((size_t)E * 4);
    if (cur > ws_size) return;

    ushort* xcat = (ushort*)(ws + o_xcat);
    ushort* bcat = (ushort*)(ws + o_bcat);
    float* we    = (float*)(ws + o_we);
    float* asr   = (float*)(ws + o_asr);
    float* adr   = (float*)(ws + o_adr);
    float* asi   = (float*)(ws + o_asi);
    float* adi   = (float*)(ws + o_adi);
    int*   flags = (int*)(ws + o_flags);
    int*   cnt8  = (int*)(ws + o_cnt8);
    int*   offA  = (int*)(ws + o_offA);
    int*   bsum  = (int*)(ws + o_bsum);
    int*   rank  = (int*)(ws + o_rank);
    uint*  escal4= (uint*)(ws + o_escal);
    uint*  csr   = (uint*)(ws + o_csr);

    int N8 = N * 8;
    bcatwe_kernel<<<257, 256, 0, stream>>>(red_W, irr_W, red_W_res, irr_W_res, bcat,
                                           red_W_edge, red_att_edge, irr_W_edge, irr_att_edge, we,
                                           cnt8, flags, N8);

    int nwords = N / 4;
    int GB = (N + 127) / 128;
    int PB = (E + 255) / 256;
    gemmprep_kernel<<<GB + PB, 256, 0, stream>>>(h, bcat, xcat,
                                                 red_att_src, red_att_dst,
                                                 irr_att_src, irr_att_dst,
                                                 asr, adr, asi, adi, N, GB,
                                                 (const uint*)reducible, nwords, flags,
                                                 dst, cnt8, rank, edge_attr, we, escal4, N, E);

    scanA_kernel<<<nb, 256, 0, stream>>>(cnt8, offA, bsum, flags + 2, N, nb);

    scatter_kernel<<<(E + 255) / 256, 256, 0, stream>>>(src, dst, rank, escal4,
                                                        reducible, flags, offA, bsum, cnt8,
                                                        csr, N, E);

    node_kernel<<<(N + 3) / 4, 256, 0, stream>>>(xcat, adr, adi, asr, asi,
                                                 reducible, flags, offA, bsum, csr,
                                                 red_bias, irr_bias, out, N, E);
}